// Round 7
// baseline (3038.751 us; speedup 1.0000x reference)
//
#include <hip/hip_runtime.h>
#include <math.h>

#define LOG2E 1.4426950408889634f
#define LN2   0.6931471805599453f

typedef short    short8  __attribute__((ext_vector_type(8)));
typedef float    floatx4 __attribute__((ext_vector_type(4)));
typedef _Float16 half8   __attribute__((ext_vector_type(8)));

__constant__ int c_pi[28] = {0,0,0,0,0,0,0,1,1,1,1,1,1,2,2,2,2,2,3,3,3,3,4,4,4,5,5,6};
__constant__ int c_pj[28] = {1,2,3,4,5,6,7,2,3,4,5,6,7,3,4,5,6,7,4,5,6,7,5,6,7,6,7,7};

// ---------------- static device storage ----------------
__device__ unsigned short g_cellsL[16*256*256];   // bf16 bits, gathered local cells
__device__ unsigned short g_cellsG[8*512*256];    // bf16 bits, gathered global cells
__device__ float g_x2L[16*256];
__device__ float g_x2G[8*512];
__device__ int   g_idxL[16*256];
__device__ int   g_idxG[8*512];
// fp16 cost matrices, no transposes. Local: [0,56)=Cxy, [56,72)=Cxx. 9.4 MB
__device__ _Float16 g_CL[72*256*256];
// Global: [0,28)=Cxy, [28,36)=Cxx. 18.9 MB
__device__ _Float16 g_CG[36*512*512];
// cross-slice exchange for global 4-block groups
__device__ unsigned long long g_xch[28][4][512];  // packed (m,s) col partials
__device__ float g_xpx[8][4][128];                // px slices
__device__ unsigned g_bar[36];                    // monotonic group barriers
__device__ float g_acc[4];                        // SL, PL, SG, PG

// ---------------- helpers ----------------
__device__ __forceinline__ unsigned short f2bf(float f) {
    unsigned u = __float_as_uint(f);
    u += 0x7fffu + ((u >> 16) & 1u);              // RNE; inputs are finite
    return (unsigned short)(u >> 16);
}
__device__ __forceinline__ void xst64(unsigned long long* p, unsigned long long v) {
    __hip_atomic_store(p, v, __ATOMIC_RELAXED, __HIP_MEMORY_SCOPE_AGENT);
}
__device__ __forceinline__ unsigned long long xld64(const unsigned long long* p) {
    return __hip_atomic_load(p, __ATOMIC_RELAXED, __HIP_MEMORY_SCOPE_AGENT);
}
__device__ __forceinline__ void xstf(float* p, float v) {
    __hip_atomic_store(p, v, __ATOMIC_RELAXED, __HIP_MEMORY_SCOPE_AGENT);
}
__device__ __forceinline__ float xldf(const float* p) {
    return __hip_atomic_load(p, __ATOMIC_RELAXED, __HIP_MEMORY_SCOPE_AGENT);
}

// ---------------- index lists ----------------
__global__ void k_index(const int* __restrict__ labels, const int* __restrict__ subg) {
    int b = blockIdx.x, lane = threadIdx.x;       // 24 blocks x 64 threads
    int want_l, want_s, cap; int* out;
    if (b < 16) { want_l = b >> 3; want_s = b & 7; cap = 256; out = g_idxL + b*256; }
    else        { want_l = -1;     want_s = b - 16; cap = 512; out = g_idxG + (b-16)*512; }
    int cnt = 0;
    for (int base = 0; base < 4096; base += 64) {
        int i = base + lane;
        bool m = (subg[i] == want_s) && (want_l < 0 || labels[i] == want_l);
        unsigned long long mask = __ballot(m);
        int pos = cnt + __popcll(mask & ((1ull << lane) - 1ull));
        if (m && pos < cap) out[pos] = i;
        cnt += __popcll(mask);
    }
}

// ---------------- gather rows -> bf16 cells + fp32 sq-norms -----------------
__global__ void k_gather(const float* __restrict__ feat) {
    int wv = blockIdx.x*4 + (threadIdx.x >> 6);   // 8192 waves, one row each
    int lane = threadIdx.x & 63;
    const float* src; unsigned short* dst; float* x2out;
    if (wv < 4096) {
        int c = wv >> 8, row = wv & 255;
        src = feat + (size_t)g_idxL[c*256+row]*256;
        dst = g_cellsL + (size_t)(c*256+row)*256;
        x2out = g_x2L + c*256 + row;
    } else {
        int v = wv - 4096; int c = v >> 9, row = v & 511;
        src = feat + (size_t)g_idxG[c*512+row]*256;
        dst = g_cellsG + (size_t)(c*512+row)*256;
        x2out = g_x2G + c*512 + row;
    }
    floatx4 v4 = *(const floatx4*)(src + lane*4);
    float s = v4[0]*v4[0] + v4[1]*v4[1] + v4[2]*v4[2] + v4[3]*v4[3];
    unsigned lo = (unsigned)f2bf(v4[0]) | ((unsigned)f2bf(v4[1]) << 16);
    unsigned hi = (unsigned)f2bf(v4[2]) | ((unsigned)f2bf(v4[3]) << 16);
    unsigned* d32 = (unsigned*)dst;
    d32[lane*2] = lo; d32[lane*2+1] = hi;
    for (int o = 32; o; o >>= 1) s += __shfl_xor(s, o);
    if (lane == 0) *x2out = s;
}

// ---------------- cost matrices via bf16 MFMA (no transposes) ---------------
__global__ void k_gemm() {
    int job = blockIdx.x*4 + (threadIdx.x >> 6);
    int lane = threadIdx.x & 63;
    const unsigned short *A, *B; _Float16* Cout; const float *x2a, *x2b;
    int m, ti, tj;
    if (job < 18432) {                            // local: 72 matrices x 256 tiles
        int mm = job >> 8, t = job & 255; ti = t >> 4; tj = t & 15; m = 256;
        int ca, cb;
        if (mm < 56) { int lbl = mm/28, q = mm%28; ca = lbl*8 + c_pi[q]; cb = lbl*8 + c_pj[q]; }
        else         { int c = mm-56; ca = cb = c; }
        A = g_cellsL + (size_t)ca*65536; B = g_cellsL + (size_t)cb*65536;
        x2a = g_x2L + ca*256; x2b = g_x2L + cb*256;
        Cout = g_CL + (size_t)mm*65536;
    } else {                                      // global: 36 matrices x 1024 tiles
        int jj = job - 18432; int mm = jj >> 10, t = jj & 1023; ti = t >> 5; tj = t & 31; m = 512;
        int ca, cb;
        if (mm < 28) { ca = c_pi[mm]; cb = c_pj[mm]; }
        else         { ca = cb = mm-28; }
        A = g_cellsG + (size_t)ca*131072; B = g_cellsG + (size_t)cb*131072;
        x2a = g_x2G + ca*512; x2b = g_x2G + cb*512;
        Cout = g_CG + (size_t)mm*262144;
    }
    int r = lane & 15, quad = lane >> 4;
    const unsigned short* Ap = A + (size_t)(ti*16 + r)*256 + quad*8;
    const unsigned short* Bp = B + (size_t)(tj*16 + r)*256 + quad*8;
    floatx4 acc = {0.f, 0.f, 0.f, 0.f};
    #pragma unroll
    for (int k = 0; k < 256; k += 32) {
        short8 av = *(const short8*)(Ap + k);
        short8 bv = *(const short8*)(Bp + k);
        acc = __builtin_amdgcn_mfma_f32_16x16x32_bf16(av, bv, acc, 0, 0, 0);
    }
    int jc = tj*16 + r;                           // D: col = lane&15, row = quad*4 + reg
    float y2 = x2b[jc];
    #pragma unroll
    for (int rr = 0; rr < 4; rr++) {
        int ir = ti*16 + quad*4 + rr;
        float v = x2a[ir] + y2 - 2.f*acc[rr];
        Cout[(size_t)ir*m + jc] = (_Float16)(0.5f*fmaxf(v, 0.f));
    }
}

// ---------------- zero barrier counters + accumulators ----------------------
__global__ void k_init() {
    int t = threadIdx.x;
    if (t < 36) g_bar[t] = 0u;
    if (t < 4)  g_acc[t] = 0.f;
}

// ---------------- group barrier (monotonic counter, agent scope) ------------
__device__ __forceinline__ void group_bar(int gid, unsigned tgt) {
    if (threadIdx.x == 0) {
        __hip_atomic_fetch_add(&g_bar[gid], 1u, __ATOMIC_RELEASE, __HIP_MEMORY_SCOPE_AGENT);
        int guard = 0;
        while (__hip_atomic_load(&g_bar[gid], __ATOMIC_ACQUIRE, __HIP_MEMORY_SCOPE_AGENT) < tgt) {
            __builtin_amdgcn_s_sleep(2);
            if (++guard > 5000000) break;         // failsafe: never hang
        }
    }
    __syncthreads();
}

// ---------------- persistent solver: C LDS-resident, 123 rounds -------------
// 216 blocks x 512 thr, 152 KB LDS, 1 block/CU -> all co-resident.
//  b <112 : global pair p=b>>2 slice q=b&3 (rows q*128..), 4-block group
//  b <144 : global Cxx  c=(b-112)>>2 slice q, 4-block group
//  b <200 : local pair p=b-144 (whole 256x256 matrix, private)
//  else   : local Cxx  c=b-200 (private)
extern __shared__ char smem[];
__global__ void __launch_bounds__(512) k_solve() {
    _Float16* sC = (_Float16*)smem;               // 131072 B
    float* scr  = (float*)(smem + 131072);        // 16384 B (4096 floats)
    float* sg   = (float*)(smem + 147456);        // [2][512] g (or px full)
    float* sf   = (float*)(smem + 151552);        // [2][512] f (slice-local)
    float* sred = (float*)(smem + 155648);        // 8 floats
    int b = blockIdx.x, tid = threadIdx.x, lane = tid & 63, w = tid >> 6;

    int role, gid = -1, q = 0;
    const _Float16* Csrc; float loga;
    if (b < 112)      { role = 2; gid = b >> 2; q = b & 3;
                        Csrc = g_CG + (size_t)gid*262144 + (size_t)q*65536;
                        loga = -6.238324625039508f; }
    else if (b < 144) { role = 3; int t = b - 112; int c = t >> 2; q = t & 3; gid = 28 + c;
                        Csrc = g_CG + (size_t)(28+c)*262144 + (size_t)q*65536;
                        loga = -6.238324625039508f; }
    else if (b < 200) { role = 0; int p = b - 144;
                        Csrc = g_CL + (size_t)p*65536;
                        loga = -5.545177444479562f; }
    else              { role = 1; int c = b - 200;
                        Csrc = g_CL + (size_t)(56+c)*65536;
                        loga = -5.545177444479562f; }

    // ---- stage C into LDS (once), zero potentials ----
    for (int i = tid; i < 8192; i += 512)
        ((floatx4*)sC)[i] = ((const floatx4*)Csrc)[i];
    for (int i = tid; i < 1024; i += 512) { sg[i] = 0.f; sf[i] = 0.f; }
    __syncthreads();

    const double ratio = 0.9*0.9;
    int po = 0;
    for (int round = 0; round < 123; round++) {
        int fin = (round == 122);
        double e = 1024.0 * pow(ratio, (double)(fin ? 121 : round));
        if (e < 1e-8) e = 1e-8;
        float ef = (float)e;
        float inv = (float)(1.0/e);
        int hard = (ef < 1e-5f) ? 1 : 0;
        float i2  = inv * LOG2E;
        float lg2 = loga * LOG2E;
        float meps = -ef * LN2;
        int pn = po ^ 1;

        if (role == 2) {                          // ---- global pair slice ----
            const float* gp = sg + po*512;
            const float* fpo = sf + po*512;
            float* fpn = sf + pn*512;
            float h2[8];
            #pragma unroll
            for (int k = 0; k < 8; k++) h2[k] = lg2 + gp[lane*8+k]*i2;
            float m2[8], ssv[8];
            #pragma unroll
            for (int k = 0; k < 8; k++) { m2[k] = -3.4e38f; ssv[k] = 0.f; }
            #pragma unroll 4
            for (int s = 0; s < 16; s++) {
                int row = w*16 + s;
                half8 cv = *(const half8*)(sC + row*512 + lane*8);
                float fr = fpo[row];
                float a2 = lg2 + fr*i2;
                float tv[8]; float mx = -3.4e38f;
                #pragma unroll
                for (int k = 0; k < 8; k++) {
                    float d = (float)cv[k]*(-i2);
                    float t = h2[k] + d; tv[k] = t; mx = fmaxf(mx, t);
                    float u = a2 + d;
                    float mn = fmaxf(m2[k], u);
                    if (!hard) ssv[k] = ssv[k]*exp2f(m2[k]-mn) + exp2f(u-mn);
                    m2[k] = mn;
                }
                #pragma unroll
                for (int o = 32; o; o >>= 1) mx = fmaxf(mx, __shfl_xor(mx, o));
                float ft;
                if (!hard) {
                    float sum = 0.f;
                    #pragma unroll
                    for (int k = 0; k < 8; k++) sum += exp2f(tv[k]-mx);
                    #pragma unroll
                    for (int o = 32; o; o >>= 1) sum += __shfl_xor(sum, o);
                    ft = meps*(mx + __log2f(sum));
                } else ft = meps*mx;
                if (lane == 0) fpn[row] = fin ? ft : 0.5f*(fr + ft);
            }
            // tree: waves 4-7 -> scr, merge by 0-3; waves 1-3 -> scr, wave 0 final
            if (w >= 4) {
                float* pm = scr + (w-4)*512; float* ps = scr + 2048 + (w-4)*512;
                #pragma unroll
                for (int k = 0; k < 8; k++) { pm[lane*8+k] = m2[k]; ps[lane*8+k] = ssv[k]; }
            }
            __syncthreads();
            if (w < 4) {
                const float* pm = scr + w*512; const float* ps = scr + 2048 + w*512;
                #pragma unroll
                for (int k = 0; k < 8; k++) {
                    float mo = pm[lane*8+k], so = ps[lane*8+k];
                    float mn = fmaxf(m2[k], mo);
                    if (!hard) ssv[k] = ssv[k]*exp2f(m2[k]-mn) + so*exp2f(mo-mn);
                    m2[k] = mn;
                }
            }
            __syncthreads();
            if (w >= 1 && w < 4) {
                float* pm = scr + (w-1)*512; float* ps = scr + 2048 + (w-1)*512;
                #pragma unroll
                for (int k = 0; k < 8; k++) { pm[lane*8+k] = m2[k]; ps[lane*8+k] = ssv[k]; }
            }
            __syncthreads();
            if (w == 0) {
                #pragma unroll
                for (int j = 0; j < 3; j++) {
                    const float* pm = scr + j*512; const float* ps = scr + 2048 + j*512;
                    #pragma unroll
                    for (int k = 0; k < 8; k++) {
                        float mo = pm[lane*8+k], so = ps[lane*8+k];
                        float mn = fmaxf(m2[k], mo);
                        if (!hard) ssv[k] = ssv[k]*exp2f(m2[k]-mn) + so*exp2f(mo-mn);
                        m2[k] = mn;
                    }
                }
                #pragma unroll
                for (int k = 0; k < 8; k++)
                    xst64(&g_xch[gid][q][lane*8+k],
                          (unsigned long long)__float_as_uint(m2[k]) |
                          ((unsigned long long)__float_as_uint(ssv[k]) << 32));
            }
            __syncthreads();
            group_bar(gid, 4u*(unsigned)(round+1));
            {
                int c = tid;
                unsigned long long v0 = xld64(&g_xch[gid][0][c]);
                unsigned long long v1 = xld64(&g_xch[gid][1][c]);
                unsigned long long v2 = xld64(&g_xch[gid][2][c]);
                unsigned long long v3 = xld64(&g_xch[gid][3][c]);
                float a0 = __uint_as_float((unsigned)v0), b0 = __uint_as_float((unsigned)(v0 >> 32));
                float a1 = __uint_as_float((unsigned)v1), b1 = __uint_as_float((unsigned)(v1 >> 32));
                float a2m = __uint_as_float((unsigned)v2), b2 = __uint_as_float((unsigned)(v2 >> 32));
                float a3 = __uint_as_float((unsigned)v3), b3 = __uint_as_float((unsigned)(v3 >> 32));
                float m = fmaxf(fmaxf(a0, a1), fmaxf(a2m, a3));
                float gt;
                if (!hard) {
                    float s = b0*exp2f(a0-m) + b1*exp2f(a1-m) + b2*exp2f(a2m-m) + b3*exp2f(a3-m);
                    gt = meps*(m + __log2f(s));
                } else gt = meps*m;
                sg[pn*512+c] = fin ? gt : 0.5f*(sg[po*512+c] + gt);
            }
            __syncthreads();
        } else if (role == 3) {                   // ---- global Cxx slice ----
            const float* pp = sg + po*512;
            float* ppn = sg + pn*512;
            float h2[8];
            #pragma unroll
            for (int k = 0; k < 8; k++) h2[k] = lg2 + pp[lane*8+k]*i2;
            #pragma unroll 4
            for (int s = 0; s < 16; s++) {
                int row = w*16 + s;
                half8 cv = *(const half8*)(sC + row*512 + lane*8);
                float tv[8]; float mx = -3.4e38f;
                #pragma unroll
                for (int k = 0; k < 8; k++) {
                    float t = h2[k] - (float)cv[k]*i2;
                    tv[k] = t; mx = fmaxf(mx, t);
                }
                #pragma unroll
                for (int o = 32; o; o >>= 1) mx = fmaxf(mx, __shfl_xor(mx, o));
                float ft;
                if (!hard) {
                    float sum = 0.f;
                    #pragma unroll
                    for (int k = 0; k < 8; k++) sum += exp2f(tv[k]-mx);
                    #pragma unroll
                    for (int o = 32; o; o >>= 1) sum += __shfl_xor(sum, o);
                    ft = meps*(mx + __log2f(sum));
                } else ft = meps*mx;
                if (lane == 0) {
                    float old = pp[q*128 + row];
                    xstf(&g_xpx[gid-28][q][row], fin ? ft : 0.5f*(old + ft));
                }
            }
            __syncthreads();
            group_bar(gid, 4u*(unsigned)(round+1));
            { int c = tid; ppn[c] = xldf(&g_xpx[gid-28][c>>7][c&127]); }
            __syncthreads();
        } else if (role == 0) {                   // ---- local pair (private) ----
            const float* gp = sg + po*512;
            const float* fpo = sf + po*512;
            float* fpn = sf + pn*512;
            int co = lane & 31, radd = lane >> 5;
            float h2[8];
            #pragma unroll
            for (int k = 0; k < 8; k++) h2[k] = lg2 + gp[co*8+k]*i2;
            float m2[8], ssv[8];
            #pragma unroll
            for (int k = 0; k < 8; k++) { m2[k] = -3.4e38f; ssv[k] = 0.f; }
            #pragma unroll 4
            for (int s = 0; s < 16; s++) {
                int row = w*32 + 2*s + radd;
                half8 cv = *(const half8*)(sC + row*256 + co*8);
                float fr = fpo[row];
                float a2 = lg2 + fr*i2;
                float tv[8]; float mx = -3.4e38f;
                #pragma unroll
                for (int k = 0; k < 8; k++) {
                    float d = (float)cv[k]*(-i2);
                    float t = h2[k] + d; tv[k] = t; mx = fmaxf(mx, t);
                    float u = a2 + d;
                    float mn = fmaxf(m2[k], u);
                    if (!hard) ssv[k] = ssv[k]*exp2f(m2[k]-mn) + exp2f(u-mn);
                    m2[k] = mn;
                }
                #pragma unroll
                for (int o = 16; o; o >>= 1) mx = fmaxf(mx, __shfl_xor(mx, o));
                float ft;
                if (!hard) {
                    float sum = 0.f;
                    #pragma unroll
                    for (int k = 0; k < 8; k++) sum += exp2f(tv[k]-mx);
                    #pragma unroll
                    for (int o = 16; o; o >>= 1) sum += __shfl_xor(sum, o);
                    ft = meps*(mx + __log2f(sum));
                } else ft = meps*mx;
                if ((lane & 31) == 0) fpn[row] = fin ? ft : 0.5f*(fr + ft);
            }
            #pragma unroll
            for (int k = 0; k < 8; k++) {         // merge half-waves (same cols)
                float mo = __shfl_xor(m2[k], 32), so = __shfl_xor(ssv[k], 32);
                float mn = fmaxf(m2[k], mo);
                if (!hard) ssv[k] = ssv[k]*exp2f(m2[k]-mn) + so*exp2f(mo-mn);
                m2[k] = mn;
            }
            if (w >= 4 && lane < 32) {
                float* pm = scr + (w-4)*256; float* ps = scr + 1024 + (w-4)*256;
                #pragma unroll
                for (int k = 0; k < 8; k++) { pm[co*8+k] = m2[k]; ps[co*8+k] = ssv[k]; }
            }
            __syncthreads();
            if (w < 4 && lane < 32) {
                const float* pm = scr + w*256; const float* ps = scr + 1024 + w*256;
                #pragma unroll
                for (int k = 0; k < 8; k++) {
                    float mo = pm[co*8+k], so = ps[co*8+k];
                    float mn = fmaxf(m2[k], mo);
                    if (!hard) ssv[k] = ssv[k]*exp2f(m2[k]-mn) + so*exp2f(mo-mn);
                    m2[k] = mn;
                }
            }
            __syncthreads();
            if (w >= 1 && w < 4 && lane < 32) {
                float* pm = scr + (w-1)*256; float* ps = scr + 1024 + (w-1)*256;
                #pragma unroll
                for (int k = 0; k < 8; k++) { pm[co*8+k] = m2[k]; ps[co*8+k] = ssv[k]; }
            }
            __syncthreads();
            if (w == 0 && lane < 32) {
                #pragma unroll
                for (int j = 0; j < 3; j++) {
                    const float* pm = scr + j*256; const float* ps = scr + 1024 + j*256;
                    #pragma unroll
                    for (int k = 0; k < 8; k++) {
                        float mo = pm[co*8+k], so = ps[co*8+k];
                        float mn = fmaxf(m2[k], mo);
                        if (!hard) ssv[k] = ssv[k]*exp2f(m2[k]-mn) + so*exp2f(mo-mn);
                        m2[k] = mn;
                    }
                }
                #pragma unroll
                for (int k = 0; k < 8; k++) {
                    int c = co*8 + k;
                    float gt = hard ? meps*m2[k] : meps*(m2[k] + __log2f(ssv[k]));
                    sg[pn*512+c] = fin ? gt : 0.5f*(sg[po*512+c] + gt);
                }
            }
            __syncthreads();
        } else {                                  // ---- local Cxx (private) ----
            const float* pp = sg + po*512;
            float* ppn = sg + pn*512;
            int co = lane & 31, radd = lane >> 5;
            float h2[8];
            #pragma unroll
            for (int k = 0; k < 8; k++) h2[k] = lg2 + pp[co*8+k]*i2;
            #pragma unroll 4
            for (int s = 0; s < 16; s++) {
                int row = w*32 + 2*s + radd;
                half8 cv = *(const half8*)(sC + row*256 + co*8);
                float tv[8]; float mx = -3.4e38f;
                #pragma unroll
                for (int k = 0; k < 8; k++) {
                    float t = h2[k] - (float)cv[k]*i2;
                    tv[k] = t; mx = fmaxf(mx, t);
                }
                #pragma unroll
                for (int o = 16; o; o >>= 1) mx = fmaxf(mx, __shfl_xor(mx, o));
                float ft;
                if (!hard) {
                    float sum = 0.f;
                    #pragma unroll
                    for (int k = 0; k < 8; k++) sum += exp2f(tv[k]-mx);
                    #pragma unroll
                    for (int o = 16; o; o >>= 1) sum += __shfl_xor(sum, o);
                    ft = meps*(mx + __log2f(sum));
                } else ft = meps*mx;
                if ((lane & 31) == 0) {
                    float old = pp[row];
                    ppn[row] = fin ? ft : 0.5f*(old + ft);
                }
            }
            __syncthreads();
        }
        po = pn;
    }

    // ---- final reduction: accumulate loss components ----
    float v = 0.f, v2 = 0.f; int idx, idx2 = -1;
    if (role == 0)      { if (tid < 256) v = sf[po*512+tid] + sg[po*512+tid]; idx = 0; }
    else if (role == 1) { if (tid < 256) v = sg[po*512+tid]; idx = 1; }
    else if (role == 2) { if (tid < 128) v = sf[po*512+tid]; idx = 2;
                          if (q == 0) { v2 = sg[po*512+tid]; idx2 = 2; } }
    else                { if (tid < 128) v = sg[po*512 + q*128 + tid]; idx = 3; }
    #pragma unroll
    for (int o = 32; o; o >>= 1) v += __shfl_xor(v, o);
    if ((tid & 63) == 0) sred[w] = v;
    __syncthreads();
    if (tid == 0) {
        float t = 0.f;
        #pragma unroll
        for (int i = 0; i < 8; i++) t += sred[i];
        atomicAdd(&g_acc[idx], t);
    }
    if (idx2 >= 0) {
        __syncthreads();
        #pragma unroll
        for (int o = 32; o; o >>= 1) v2 += __shfl_xor(v2, o);
        if ((tid & 63) == 0) sred[w] = v2;
        __syncthreads();
        if (tid == 0) {
            float t = 0.f;
            #pragma unroll
            for (int i = 0; i < 8; i++) t += sred[i];
            atomicAdd(&g_acc[idx2], t);
        }
    }
}

// ---------------- final combine ---------------------------------------------
__global__ void k_combine(float* __restrict__ out) {
    if (threadIdx.x == 0) {
        float SL = g_acc[0], PL = g_acc[1], SG = g_acc[2], PG = g_acc[3];
        out[0] = (SL/14336.f - PL/2048.f) + 0.5f*(SG/14336.f - PG/2048.f);
    }
}

// ---------------- host launcher ---------------------------------------------
extern "C" void kernel_launch(void* const* d_in, const int* in_sizes, int n_in,
                              void* d_out, int out_size, void* d_ws, size_t ws_size,
                              hipStream_t stream) {
    (void)in_sizes; (void)n_in; (void)out_size; (void)d_ws; (void)ws_size;
    const float* feat  = (const float*)d_in[0];
    const int* labels  = (const int*)d_in[1];
    const int* subg    = (const int*)d_in[2];

    static int attr_set = 0;
    if (!attr_set) {
        hipFuncSetAttribute((const void*)k_solve,
                            hipFuncAttributeMaxDynamicSharedMemorySize, 155712);
        attr_set = 1;
    }

    k_index <<<24,    64, 0, stream>>>(labels, subg);
    k_gather<<<2048, 256, 0, stream>>>(feat);
    k_gemm  <<<13824,256, 0, stream>>>();
    k_init  <<<1,     64, 0, stream>>>();
    k_solve <<<216,  512, 155712, stream>>>();
    k_combine<<<1,    64, 0, stream>>>((float*)d_out);
}

// Round 8
// 2997.755 us; speedup vs baseline: 1.0137x; 1.0137x over previous
//
#include <hip/hip_runtime.h>
#include <math.h>

#define LOG2E 1.4426950408889634f
#define LN2   0.6931471805599453f

typedef short    short8  __attribute__((ext_vector_type(8)));
typedef float    floatx4 __attribute__((ext_vector_type(4)));
typedef _Float16 half8   __attribute__((ext_vector_type(8)));

__constant__ int c_pi[28] = {0,0,0,0,0,0,0,1,1,1,1,1,1,2,2,2,2,2,3,3,3,3,4,4,4,5,5,6};
__constant__ int c_pj[28] = {1,2,3,4,5,6,7,2,3,4,5,6,7,3,4,5,6,7,4,5,6,7,5,6,7,6,7,7};

// ---------------- static device storage ----------------
__device__ unsigned short g_cellsL[16*256*256];   // bf16 bits, gathered local cells
__device__ unsigned short g_cellsG[8*512*256];    // bf16 bits, gathered global cells
__device__ float g_x2L[16*256];
__device__ float g_x2G[8*512];
__device__ int   g_idxL[16*256];
__device__ int   g_idxG[8*512];
// fp16 cost matrices, no transposes. Local: [0,56)=Cxy, [56,72)=Cxx. 9.4 MB
__device__ _Float16 g_CL[72*256*256];
// Global: [0,28)=Cxy, [28,36)=Cxx. 18.9 MB
__device__ _Float16 g_CG[36*512*512];
// cross-slice exchange for global 4-block groups (double-buffered by round)
__device__ unsigned long long g_xch[28][2][4][512]; // packed (m,s) col partials
__device__ float g_xpx[8][2][4][128];               // px slices
__device__ unsigned g_bar[36];                      // monotonic group barriers
__device__ float g_acc[4];                          // SL, PL, SG, PG
__device__ float g_efT[122], g_ivT[122];            // eps schedule table

// ---------------- helpers ----------------
__device__ __forceinline__ unsigned short f2bf(float f) {
    unsigned u = __float_as_uint(f);
    u += 0x7fffu + ((u >> 16) & 1u);              // RNE; inputs are finite
    return (unsigned short)(u >> 16);
}
// relaxed agent-scope (sc1, L2-bypass -> cross-XCD coherent, NO inv/wb)
__device__ __forceinline__ void xst64(unsigned long long* p, unsigned long long v) {
    __hip_atomic_store(p, v, __ATOMIC_RELAXED, __HIP_MEMORY_SCOPE_AGENT);
}
__device__ __forceinline__ unsigned long long xld64(const unsigned long long* p) {
    return __hip_atomic_load(p, __ATOMIC_RELAXED, __HIP_MEMORY_SCOPE_AGENT);
}
__device__ __forceinline__ void xstf(float* p, float v) {
    __hip_atomic_store(p, v, __ATOMIC_RELAXED, __HIP_MEMORY_SCOPE_AGENT);
}
__device__ __forceinline__ float xldf(const float* p) {
    return __hip_atomic_load(p, __ATOMIC_RELAXED, __HIP_MEMORY_SCOPE_AGENT);
}

// ---------------- index lists ----------------
__global__ void k_index(const int* __restrict__ labels, const int* __restrict__ subg) {
    int b = blockIdx.x, lane = threadIdx.x;       // 24 blocks x 64 threads
    int want_l, want_s, cap; int* out;
    if (b < 16) { want_l = b >> 3; want_s = b & 7; cap = 256; out = g_idxL + b*256; }
    else        { want_l = -1;     want_s = b - 16; cap = 512; out = g_idxG + (b-16)*512; }
    int cnt = 0;
    for (int base = 0; base < 4096; base += 64) {
        int i = base + lane;
        bool m = (subg[i] == want_s) && (want_l < 0 || labels[i] == want_l);
        unsigned long long mask = __ballot(m);
        int pos = cnt + __popcll(mask & ((1ull << lane) - 1ull));
        if (m && pos < cap) out[pos] = i;
        cnt += __popcll(mask);
    }
}

// ---------------- gather rows -> bf16 cells + fp32 sq-norms -----------------
__global__ void k_gather(const float* __restrict__ feat) {
    int wv = blockIdx.x*4 + (threadIdx.x >> 6);   // 8192 waves, one row each
    int lane = threadIdx.x & 63;
    const float* src; unsigned short* dst; float* x2out;
    if (wv < 4096) {
        int c = wv >> 8, row = wv & 255;
        src = feat + (size_t)g_idxL[c*256+row]*256;
        dst = g_cellsL + (size_t)(c*256+row)*256;
        x2out = g_x2L + c*256 + row;
    } else {
        int v = wv - 4096; int c = v >> 9, row = v & 511;
        src = feat + (size_t)g_idxG[c*512+row]*256;
        dst = g_cellsG + (size_t)(c*512+row)*256;
        x2out = g_x2G + c*512 + row;
    }
    floatx4 v4 = *(const floatx4*)(src + lane*4);
    float s = v4[0]*v4[0] + v4[1]*v4[1] + v4[2]*v4[2] + v4[3]*v4[3];
    unsigned lo = (unsigned)f2bf(v4[0]) | ((unsigned)f2bf(v4[1]) << 16);
    unsigned hi = (unsigned)f2bf(v4[2]) | ((unsigned)f2bf(v4[3]) << 16);
    unsigned* d32 = (unsigned*)dst;
    d32[lane*2] = lo; d32[lane*2+1] = hi;
    for (int o = 32; o; o >>= 1) s += __shfl_xor(s, o);
    if (lane == 0) *x2out = s;
}

// ---------------- cost matrices via bf16 MFMA (no transposes) ---------------
__global__ void k_gemm() {
    int job = blockIdx.x*4 + (threadIdx.x >> 6);
    int lane = threadIdx.x & 63;
    const unsigned short *A, *B; _Float16* Cout; const float *x2a, *x2b;
    int m, ti, tj;
    if (job < 18432) {                            // local: 72 matrices x 256 tiles
        int mm = job >> 8, t = job & 255; ti = t >> 4; tj = t & 15; m = 256;
        int ca, cb;
        if (mm < 56) { int lbl = mm/28, q = mm%28; ca = lbl*8 + c_pi[q]; cb = lbl*8 + c_pj[q]; }
        else         { int c = mm-56; ca = cb = c; }
        A = g_cellsL + (size_t)ca*65536; B = g_cellsL + (size_t)cb*65536;
        x2a = g_x2L + ca*256; x2b = g_x2L + cb*256;
        Cout = g_CL + (size_t)mm*65536;
    } else {                                      // global: 36 matrices x 1024 tiles
        int jj = job - 18432; int mm = jj >> 10, t = jj & 1023; ti = t >> 5; tj = t & 31; m = 512;
        int ca, cb;
        if (mm < 28) { ca = c_pi[mm]; cb = c_pj[mm]; }
        else         { ca = cb = mm-28; }
        A = g_cellsG + (size_t)ca*131072; B = g_cellsG + (size_t)cb*131072;
        x2a = g_x2G + ca*512; x2b = g_x2G + cb*512;
        Cout = g_CG + (size_t)mm*262144;
    }
    int r = lane & 15, quad = lane >> 4;
    const unsigned short* Ap = A + (size_t)(ti*16 + r)*256 + quad*8;
    const unsigned short* Bp = B + (size_t)(tj*16 + r)*256 + quad*8;
    floatx4 acc = {0.f, 0.f, 0.f, 0.f};
    #pragma unroll
    for (int k = 0; k < 256; k += 32) {
        short8 av = *(const short8*)(Ap + k);
        short8 bv = *(const short8*)(Bp + k);
        acc = __builtin_amdgcn_mfma_f32_16x16x32_bf16(av, bv, acc, 0, 0, 0);
    }
    int jc = tj*16 + r;                           // D: col = lane&15, row = quad*4 + reg
    float y2 = x2b[jc];
    #pragma unroll
    for (int rr = 0; rr < 4; rr++) {
        int ir = ti*16 + quad*4 + rr;
        float v = x2a[ir] + y2 - 2.f*acc[rr];
        Cout[(size_t)ir*m + jc] = (_Float16)(0.5f*fmaxf(v, 0.f));
    }
}

// ---------------- init: barriers, accumulators, eps table -------------------
__global__ void k_init() {
    int t = threadIdx.x;                          // 128 threads
    if (t < 36) g_bar[t] = 0u;
    if (t < 4)  g_acc[t] = 0.f;
    if (t < 122) {                                // same double math as reference
        double e = 1024.0 * pow(0.81, (double)t);
        if (e < 1e-8) e = 1e-8;
        g_efT[t] = (float)e;
        g_ivT[t] = (float)(1.0/e);
    }
}

// ---------------- group barrier (relaxed monotonic counter) -----------------
// Data stores are sc1 (coherence-point) ops; vmcnt(0) drains them before the
// relaxed increment, so a partner observing the count sees the data. No
// acquire/release -> no L2 invalidate/writeback storms (round-7 lesson).
__device__ __forceinline__ void group_bar(int gid, unsigned tgt) {
    if (threadIdx.x == 0) {
        asm volatile("s_waitcnt vmcnt(0)" ::: "memory");
        __hip_atomic_fetch_add(&g_bar[gid], 1u, __ATOMIC_RELAXED, __HIP_MEMORY_SCOPE_AGENT);
        int guard = 0;
        while (__hip_atomic_load(&g_bar[gid], __ATOMIC_RELAXED, __HIP_MEMORY_SCOPE_AGENT) < tgt) {
            __builtin_amdgcn_s_sleep(8);
            if (++guard > 5000000) break;         // failsafe: never hang
        }
    }
    __syncthreads();
}

// ---------------- persistent solver: C LDS-resident, 123 rounds -------------
// 216 blocks x 512 thr, 152 KB LDS, 1 block/CU -> all co-resident.
//  b <112 : global pair p=b>>2 slice q=b&3 (rows q*128..), 4-block group
//  b <144 : global Cxx  c=(b-112)>>2 slice q, 4-block group
//  b <200 : local pair p=b-144 (whole 256x256 matrix, private)
//  else   : local Cxx  c=b-200 (private)
extern __shared__ char smem[];
__global__ void __launch_bounds__(512) k_solve() {
    _Float16* sC = (_Float16*)smem;               // 131072 B
    float* scr  = (float*)(smem + 131072);        // 16384 B (4096 floats)
    float* sg   = (float*)(smem + 147456);        // [2][512] g (or px full)
    float* sf   = (float*)(smem + 151552);        // [2][512] f (slice-local)
    float* sred = (float*)(smem + 155648);        // 8 floats
    int b = blockIdx.x, tid = threadIdx.x, lane = tid & 63, w = tid >> 6;

    int role, gid = -1, q = 0;
    const _Float16* Csrc; float loga;
    if (b < 112)      { role = 2; gid = b >> 2; q = b & 3;
                        Csrc = g_CG + (size_t)gid*262144 + (size_t)q*65536;
                        loga = -6.238324625039508f; }
    else if (b < 144) { role = 3; int t = b - 112; int c = t >> 2; q = t & 3; gid = 28 + c;
                        Csrc = g_CG + (size_t)(28+c)*262144 + (size_t)q*65536;
                        loga = -6.238324625039508f; }
    else if (b < 200) { role = 0; int p = b - 144;
                        Csrc = g_CL + (size_t)p*65536;
                        loga = -5.545177444479562f; }
    else              { role = 1; int c = b - 200;
                        Csrc = g_CL + (size_t)(56+c)*65536;
                        loga = -5.545177444479562f; }

    // ---- stage C into LDS (once), zero potentials ----
    for (int i = tid; i < 8192; i += 512)
        ((floatx4*)sC)[i] = ((const floatx4*)Csrc)[i];
    for (int i = tid; i < 1024; i += 512) { sg[i] = 0.f; sf[i] = 0.f; }
    __syncthreads();

    int po = 0;
    for (int round = 0; round < 123; round++) {
        int fin = (round == 122);
        int ei = fin ? 121 : round;
        float ef  = g_efT[ei];
        float inv = g_ivT[ei];
        int hard = (ef < 1e-5f) ? 1 : 0;
        float i2  = inv * LOG2E;
        float lg2 = loga * LOG2E;
        float meps = -ef * LN2;
        int pn = po ^ 1;
        int rb = round & 1;                       // exchange double-buffer

        if (role == 2) {                          // ---- global pair slice ----
            const float* gp = sg + po*512;
            const float* fpo = sf + po*512;
            float* fpn = sf + pn*512;
            float h2[8];
            #pragma unroll
            for (int k = 0; k < 8; k++) h2[k] = lg2 + gp[lane*8+k]*i2;
            float m2[8], ssv[8];
            #pragma unroll
            for (int k = 0; k < 8; k++) { m2[k] = -3.4e38f; ssv[k] = 0.f; }
            #pragma unroll 4
            for (int s = 0; s < 16; s++) {
                int row = w*16 + s;
                half8 cv = *(const half8*)(sC + row*512 + lane*8);
                float fr = fpo[row];
                float a2 = lg2 + fr*i2;
                float tv[8]; float mx = -3.4e38f;
                #pragma unroll
                for (int k = 0; k < 8; k++) {
                    float d = (float)cv[k]*(-i2);
                    float t = h2[k] + d; tv[k] = t; mx = fmaxf(mx, t);
                    float u = a2 + d;
                    float mn = fmaxf(m2[k], u);
                    if (!hard) ssv[k] = ssv[k]*exp2f(m2[k]-mn) + exp2f(u-mn);
                    m2[k] = mn;
                }
                #pragma unroll
                for (int o = 32; o; o >>= 1) mx = fmaxf(mx, __shfl_xor(mx, o));
                float ft;
                if (!hard) {
                    float sum = 0.f;
                    #pragma unroll
                    for (int k = 0; k < 8; k++) sum += exp2f(tv[k]-mx);
                    #pragma unroll
                    for (int o = 32; o; o >>= 1) sum += __shfl_xor(sum, o);
                    ft = meps*(mx + __log2f(sum));
                } else ft = meps*mx;
                if (lane == 0) fpn[row] = fin ? ft : 0.5f*(fr + ft);
            }
            // tree: waves 4-7 -> scr, merge by 0-3; waves 1-3 -> scr, wave 0 final
            if (w >= 4) {
                float* pm = scr + (w-4)*512; float* ps = scr + 2048 + (w-4)*512;
                #pragma unroll
                for (int k = 0; k < 8; k++) { pm[lane*8+k] = m2[k]; ps[lane*8+k] = ssv[k]; }
            }
            __syncthreads();
            if (w < 4) {
                const float* pm = scr + w*512; const float* ps = scr + 2048 + w*512;
                #pragma unroll
                for (int k = 0; k < 8; k++) {
                    float mo = pm[lane*8+k], so = ps[lane*8+k];
                    float mn = fmaxf(m2[k], mo);
                    if (!hard) ssv[k] = ssv[k]*exp2f(m2[k]-mn) + so*exp2f(mo-mn);
                    m2[k] = mn;
                }
            }
            __syncthreads();
            if (w >= 1 && w < 4) {
                float* pm = scr + (w-1)*512; float* ps = scr + 2048 + (w-1)*512;
                #pragma unroll
                for (int k = 0; k < 8; k++) { pm[lane*8+k] = m2[k]; ps[lane*8+k] = ssv[k]; }
            }
            __syncthreads();
            if (w == 0) {
                #pragma unroll
                for (int j = 0; j < 3; j++) {
                    const float* pm = scr + j*512; const float* ps = scr + 2048 + j*512;
                    #pragma unroll
                    for (int k = 0; k < 8; k++) {
                        float mo = pm[lane*8+k], so = ps[lane*8+k];
                        float mn = fmaxf(m2[k], mo);
                        if (!hard) ssv[k] = ssv[k]*exp2f(m2[k]-mn) + so*exp2f(mo-mn);
                        m2[k] = mn;
                    }
                }
                #pragma unroll
                for (int k = 0; k < 8; k++)
                    xst64(&g_xch[gid][rb][q][lane*8+k],
                          (unsigned long long)__float_as_uint(m2[k]) |
                          ((unsigned long long)__float_as_uint(ssv[k]) << 32));
            }
            __syncthreads();
            group_bar(gid, 4u*(unsigned)(round+1));
            {
                int c = tid;
                unsigned long long v0 = xld64(&g_xch[gid][rb][0][c]);
                unsigned long long v1 = xld64(&g_xch[gid][rb][1][c]);
                unsigned long long v2 = xld64(&g_xch[gid][rb][2][c]);
                unsigned long long v3 = xld64(&g_xch[gid][rb][3][c]);
                float a0 = __uint_as_float((unsigned)v0), b0 = __uint_as_float((unsigned)(v0 >> 32));
                float a1 = __uint_as_float((unsigned)v1), b1 = __uint_as_float((unsigned)(v1 >> 32));
                float a2m = __uint_as_float((unsigned)v2), b2 = __uint_as_float((unsigned)(v2 >> 32));
                float a3 = __uint_as_float((unsigned)v3), b3 = __uint_as_float((unsigned)(v3 >> 32));
                float m = fmaxf(fmaxf(a0, a1), fmaxf(a2m, a3));
                float gt;
                if (!hard) {
                    float s = b0*exp2f(a0-m) + b1*exp2f(a1-m) + b2*exp2f(a2m-m) + b3*exp2f(a3-m);
                    gt = meps*(m + __log2f(s));
                } else gt = meps*m;
                sg[pn*512+c] = fin ? gt : 0.5f*(sg[po*512+c] + gt);
            }
            __syncthreads();
        } else if (role == 3) {                   // ---- global Cxx slice ----
            const float* pp = sg + po*512;
            float* ppn = sg + pn*512;
            float h2[8];
            #pragma unroll
            for (int k = 0; k < 8; k++) h2[k] = lg2 + pp[lane*8+k]*i2;
            #pragma unroll 4
            for (int s = 0; s < 16; s++) {
                int row = w*16 + s;
                half8 cv = *(const half8*)(sC + row*512 + lane*8);
                float tv[8]; float mx = -3.4e38f;
                #pragma unroll
                for (int k = 0; k < 8; k++) {
                    float t = h2[k] - (float)cv[k]*i2;
                    tv[k] = t; mx = fmaxf(mx, t);
                }
                #pragma unroll
                for (int o = 32; o; o >>= 1) mx = fmaxf(mx, __shfl_xor(mx, o));
                float ft;
                if (!hard) {
                    float sum = 0.f;
                    #pragma unroll
                    for (int k = 0; k < 8; k++) sum += exp2f(tv[k]-mx);
                    #pragma unroll
                    for (int o = 32; o; o >>= 1) sum += __shfl_xor(sum, o);
                    ft = meps*(mx + __log2f(sum));
                } else ft = meps*mx;
                if (lane == 0) {
                    float old = pp[q*128 + row];
                    xstf(&g_xpx[gid-28][rb][q][row], fin ? ft : 0.5f*(old + ft));
                }
            }
            __syncthreads();
            group_bar(gid, 4u*(unsigned)(round+1));
            { int c = tid; ppn[c] = xldf(&g_xpx[gid-28][rb][c>>7][c&127]); }
            __syncthreads();
        } else if (role == 0) {                   // ---- local pair (private) ----
            const float* gp = sg + po*512;
            const float* fpo = sf + po*512;
            float* fpn = sf + pn*512;
            int co = lane & 31, radd = lane >> 5;
            float h2[8];
            #pragma unroll
            for (int k = 0; k < 8; k++) h2[k] = lg2 + gp[co*8+k]*i2;
            float m2[8], ssv[8];
            #pragma unroll
            for (int k = 0; k < 8; k++) { m2[k] = -3.4e38f; ssv[k] = 0.f; }
            #pragma unroll 4
            for (int s = 0; s < 16; s++) {
                int row = w*32 + 2*s + radd;
                half8 cv = *(const half8*)(sC + row*256 + co*8);
                float fr = fpo[row];
                float a2 = lg2 + fr*i2;
                float tv[8]; float mx = -3.4e38f;
                #pragma unroll
                for (int k = 0; k < 8; k++) {
                    float d = (float)cv[k]*(-i2);
                    float t = h2[k] + d; tv[k] = t; mx = fmaxf(mx, t);
                    float u = a2 + d;
                    float mn = fmaxf(m2[k], u);
                    if (!hard) ssv[k] = ssv[k]*exp2f(m2[k]-mn) + exp2f(u-mn);
                    m2[k] = mn;
                }
                #pragma unroll
                for (int o = 16; o; o >>= 1) mx = fmaxf(mx, __shfl_xor(mx, o));
                float ft;
                if (!hard) {
                    float sum = 0.f;
                    #pragma unroll
                    for (int k = 0; k < 8; k++) sum += exp2f(tv[k]-mx);
                    #pragma unroll
                    for (int o = 16; o; o >>= 1) sum += __shfl_xor(sum, o);
                    ft = meps*(mx + __log2f(sum));
                } else ft = meps*mx;
                if ((lane & 31) == 0) fpn[row] = fin ? ft : 0.5f*(fr + ft);
            }
            #pragma unroll
            for (int k = 0; k < 8; k++) {         // merge half-waves (same cols)
                float mo = __shfl_xor(m2[k], 32), so = __shfl_xor(ssv[k], 32);
                float mn = fmaxf(m2[k], mo);
                if (!hard) ssv[k] = ssv[k]*exp2f(m2[k]-mn) + so*exp2f(mo-mn);
                m2[k] = mn;
            }
            if (w >= 4 && lane < 32) {
                float* pm = scr + (w-4)*256; float* ps = scr + 1024 + (w-4)*256;
                #pragma unroll
                for (int k = 0; k < 8; k++) { pm[co*8+k] = m2[k]; ps[co*8+k] = ssv[k]; }
            }
            __syncthreads();
            if (w < 4 && lane < 32) {
                const float* pm = scr + w*256; const float* ps = scr + 1024 + w*256;
                #pragma unroll
                for (int k = 0; k < 8; k++) {
                    float mo = pm[co*8+k], so = ps[co*8+k];
                    float mn = fmaxf(m2[k], mo);
                    if (!hard) ssv[k] = ssv[k]*exp2f(m2[k]-mn) + so*exp2f(mo-mn);
                    m2[k] = mn;
                }
            }
            __syncthreads();
            if (w >= 1 && w < 4 && lane < 32) {
                float* pm = scr + (w-1)*256; float* ps = scr + 1024 + (w-1)*256;
                #pragma unroll
                for (int k = 0; k < 8; k++) { pm[co*8+k] = m2[k]; ps[co*8+k] = ssv[k]; }
            }
            __syncthreads();
            if (w == 0 && lane < 32) {
                #pragma unroll
                for (int j = 0; j < 3; j++) {
                    const float* pm = scr + j*256; const float* ps = scr + 1024 + j*256;
                    #pragma unroll
                    for (int k = 0; k < 8; k++) {
                        float mo = pm[co*8+k], so = ps[co*8+k];
                        float mn = fmaxf(m2[k], mo);
                        if (!hard) ssv[k] = ssv[k]*exp2f(m2[k]-mn) + so*exp2f(mo-mn);
                        m2[k] = mn;
                    }
                }
                #pragma unroll
                for (int k = 0; k < 8; k++) {
                    int c = co*8 + k;
                    float gt = hard ? meps*m2[k] : meps*(m2[k] + __log2f(ssv[k]));
                    sg[pn*512+c] = fin ? gt : 0.5f*(sg[po*512+c] + gt);
                }
            }
            __syncthreads();
        } else {                                  // ---- local Cxx (private) ----
            const float* pp = sg + po*512;
            float* ppn = sg + pn*512;
            int co = lane & 31, radd = lane >> 5;
            float h2[8];
            #pragma unroll
            for (int k = 0; k < 8; k++) h2[k] = lg2 + pp[co*8+k]*i2;
            #pragma unroll 4
            for (int s = 0; s < 16; s++) {
                int row = w*32 + 2*s + radd;
                half8 cv = *(const half8*)(sC + row*256 + co*8);
                float tv[8]; float mx = -3.4e38f;
                #pragma unroll
                for (int k = 0; k < 8; k++) {
                    float t = h2[k] - (float)cv[k]*i2;
                    tv[k] = t; mx = fmaxf(mx, t);
                }
                #pragma unroll
                for (int o = 16; o; o >>= 1) mx = fmaxf(mx, __shfl_xor(mx, o));
                float ft;
                if (!hard) {
                    float sum = 0.f;
                    #pragma unroll
                    for (int k = 0; k < 8; k++) sum += exp2f(tv[k]-mx);
                    #pragma unroll
                    for (int o = 16; o; o >>= 1) sum += __shfl_xor(sum, o);
                    ft = meps*(mx + __log2f(sum));
                } else ft = meps*mx;
                if ((lane & 31) == 0) {
                    float old = pp[row];
                    ppn[row] = fin ? ft : 0.5f*(old + ft);
                }
            }
            __syncthreads();
        }
        po = pn;
    }

    // ---- final reduction: accumulate loss components ----
    float v = 0.f, v2 = 0.f; int idx, idx2 = -1;
    if (role == 0)      { if (tid < 256) v = sf[po*512+tid] + sg[po*512+tid]; idx = 0; }
    else if (role == 1) { if (tid < 256) v = sg[po*512+tid]; idx = 1; }
    else if (role == 2) { if (tid < 128) v = sf[po*512+tid]; idx = 2;
                          if (q == 0) { v2 = sg[po*512+tid]; idx2 = 2; } }
    else                { if (tid < 128) v = sg[po*512 + q*128 + tid]; idx = 3; }
    #pragma unroll
    for (int o = 32; o; o >>= 1) v += __shfl_xor(v, o);
    if ((tid & 63) == 0) sred[w] = v;
    __syncthreads();
    if (tid == 0) {
        float t = 0.f;
        #pragma unroll
        for (int i = 0; i < 8; i++) t += sred[i];
        atomicAdd(&g_acc[idx], t);
    }
    if (idx2 >= 0) {
        __syncthreads();
        #pragma unroll
        for (int o = 32; o; o >>= 1) v2 += __shfl_xor(v2, o);
        if ((tid & 63) == 0) sred[w] = v2;
        __syncthreads();
        if (tid == 0) {
            float t = 0.f;
            #pragma unroll
            for (int i = 0; i < 8; i++) t += sred[i];
            atomicAdd(&g_acc[idx2], t);
        }
    }
}

// ---------------- final combine ---------------------------------------------
__global__ void k_combine(float* __restrict__ out) {
    if (threadIdx.x == 0) {
        float SL = g_acc[0], PL = g_acc[1], SG = g_acc[2], PG = g_acc[3];
        out[0] = (SL/14336.f - PL/2048.f) + 0.5f*(SG/14336.f - PG/2048.f);
    }
}

// ---------------- host launcher ---------------------------------------------
extern "C" void kernel_launch(void* const* d_in, const int* in_sizes, int n_in,
                              void* d_out, int out_size, void* d_ws, size_t ws_size,
                              hipStream_t stream) {
    (void)in_sizes; (void)n_in; (void)out_size; (void)d_ws; (void)ws_size;
    const float* feat  = (const float*)d_in[0];
    const int* labels  = (const int*)d_in[1];
    const int* subg    = (const int*)d_in[2];

    static int attr_set = 0;
    if (!attr_set) {
        hipFuncSetAttribute((const void*)k_solve,
                            hipFuncAttributeMaxDynamicSharedMemorySize, 155712);
        attr_set = 1;
    }

    k_index <<<24,    64, 0, stream>>>(labels, subg);
    k_gather<<<2048, 256, 0, stream>>>(feat);
    k_gemm  <<<13824,256, 0, stream>>>();
    k_init  <<<1,    128, 0, stream>>>();
    k_solve <<<216,  512, 155712, stream>>>();
    k_combine<<<1,    64, 0, stream>>>((float*)d_out);
}

// Round 9
// 2817.613 us; speedup vs baseline: 1.0785x; 1.0639x over previous
//
#include <hip/hip_runtime.h>
#include <math.h>

#define LOG2E 1.4426950408889634f
#define LN2   0.6931471805599453f

typedef short    short8  __attribute__((ext_vector_type(8)));
typedef float    floatx4 __attribute__((ext_vector_type(4)));
typedef _Float16 half8   __attribute__((ext_vector_type(8)));

__constant__ int c_pi[28] = {0,0,0,0,0,0,0,1,1,1,1,1,1,2,2,2,2,2,3,3,3,3,4,4,4,5,5,6};
__constant__ int c_pj[28] = {1,2,3,4,5,6,7,2,3,4,5,6,7,3,4,5,6,7,4,5,6,7,5,6,7,6,7,7};

// ---------------- static device storage ----------------
__device__ unsigned short g_cellsL[16*256*256];   // bf16 bits, gathered local cells
__device__ unsigned short g_cellsG[8*512*256];    // bf16 bits, gathered global cells
__device__ float g_x2L[16*256];
__device__ float g_x2G[8*512];
__device__ int   g_idxL[16*256];
__device__ int   g_idxG[8*512];
// fp16 cost matrices, no transposes. Local: [0,56)=Cxy, [56,72)=Cxx. 9.4 MB
__device__ _Float16 g_CL[72*256*256];
// Global: [0,28)=Cxy, [28,36)=Cxx. 18.9 MB
__device__ _Float16 g_CG[36*512*512];
// cross-slice exchange for global 4-block groups (double-buffered by round)
__device__ unsigned long long g_xch[28][2][4][512]; // packed (m,s) col partials
__device__ float g_xpx[8][2][4][128];               // px slices
__device__ unsigned g_bar[36];                      // monotonic group barriers
__device__ float g_acc[4];                          // SL, PL, SG, PG
__device__ float g_efT[122], g_ivT[122];            // eps schedule table

// ---------------- helpers ----------------
__device__ __forceinline__ unsigned short f2bf(float f) {
    unsigned u = __float_as_uint(f);
    u += 0x7fffu + ((u >> 16) & 1u);              // RNE; inputs are finite
    return (unsigned short)(u >> 16);
}
// relaxed agent-scope (bypass L2 -> cross-XCD coherent)
__device__ __forceinline__ void xst64(unsigned long long* p, unsigned long long v) {
    __hip_atomic_store(p, v, __ATOMIC_RELAXED, __HIP_MEMORY_SCOPE_AGENT);
}
__device__ __forceinline__ unsigned long long xld64(const unsigned long long* p) {
    return __hip_atomic_load(p, __ATOMIC_RELAXED, __HIP_MEMORY_SCOPE_AGENT);
}
__device__ __forceinline__ void xstf(float* p, float v) {
    __hip_atomic_store(p, v, __ATOMIC_RELAXED, __HIP_MEMORY_SCOPE_AGENT);
}
__device__ __forceinline__ float xldf(const float* p) {
    return __hip_atomic_load(p, __ATOMIC_RELAXED, __HIP_MEMORY_SCOPE_AGENT);
}

// ---------------- index lists ----------------
__global__ void k_index(const int* __restrict__ labels, const int* __restrict__ subg) {
    int b = blockIdx.x, lane = threadIdx.x;       // 24 blocks x 64 threads
    int want_l, want_s, cap; int* out;
    if (b < 16) { want_l = b >> 3; want_s = b & 7; cap = 256; out = g_idxL + b*256; }
    else        { want_l = -1;     want_s = b - 16; cap = 512; out = g_idxG + (b-16)*512; }
    int cnt = 0;
    for (int base = 0; base < 4096; base += 64) {
        int i = base + lane;
        bool m = (subg[i] == want_s) && (want_l < 0 || labels[i] == want_l);
        unsigned long long mask = __ballot(m);
        int pos = cnt + __popcll(mask & ((1ull << lane) - 1ull));
        if (m && pos < cap) out[pos] = i;
        cnt += __popcll(mask);
    }
}

// ---------------- gather rows -> bf16 cells + fp32 sq-norms -----------------
__global__ void k_gather(const float* __restrict__ feat) {
    int wv = blockIdx.x*4 + (threadIdx.x >> 6);   // 8192 waves, one row each
    int lane = threadIdx.x & 63;
    const float* src; unsigned short* dst; float* x2out;
    if (wv < 4096) {
        int c = wv >> 8, row = wv & 255;
        src = feat + (size_t)g_idxL[c*256+row]*256;
        dst = g_cellsL + (size_t)(c*256+row)*256;
        x2out = g_x2L + c*256 + row;
    } else {
        int v = wv - 4096; int c = v >> 9, row = v & 511;
        src = feat + (size_t)g_idxG[c*512+row]*256;
        dst = g_cellsG + (size_t)(c*512+row)*256;
        x2out = g_x2G + c*512 + row;
    }
    floatx4 v4 = *(const floatx4*)(src + lane*4);
    float s = v4[0]*v4[0] + v4[1]*v4[1] + v4[2]*v4[2] + v4[3]*v4[3];
    unsigned lo = (unsigned)f2bf(v4[0]) | ((unsigned)f2bf(v4[1]) << 16);
    unsigned hi = (unsigned)f2bf(v4[2]) | ((unsigned)f2bf(v4[3]) << 16);
    unsigned* d32 = (unsigned*)dst;
    d32[lane*2] = lo; d32[lane*2+1] = hi;
    for (int o = 32; o; o >>= 1) s += __shfl_xor(s, o);
    if (lane == 0) *x2out = s;
}

// ---------------- cost matrices via bf16 MFMA (no transposes) ---------------
__global__ void k_gemm() {
    int job = blockIdx.x*4 + (threadIdx.x >> 6);
    int lane = threadIdx.x & 63;
    const unsigned short *A, *B; _Float16* Cout; const float *x2a, *x2b;
    int m, ti, tj;
    if (job < 18432) {                            // local: 72 matrices x 256 tiles
        int mm = job >> 8, t = job & 255; ti = t >> 4; tj = t & 15; m = 256;
        int ca, cb;
        if (mm < 56) { int lbl = mm/28, q = mm%28; ca = lbl*8 + c_pi[q]; cb = lbl*8 + c_pj[q]; }
        else         { int c = mm-56; ca = cb = c; }
        A = g_cellsL + (size_t)ca*65536; B = g_cellsL + (size_t)cb*65536;
        x2a = g_x2L + ca*256; x2b = g_x2L + cb*256;
        Cout = g_CL + (size_t)mm*65536;
    } else {                                      // global: 36 matrices x 1024 tiles
        int jj = job - 18432; int mm = jj >> 10, t = jj & 1023; ti = t >> 5; tj = t & 31; m = 512;
        int ca, cb;
        if (mm < 28) { ca = c_pi[mm]; cb = c_pj[mm]; }
        else         { ca = cb = mm-28; }
        A = g_cellsG + (size_t)ca*131072; B = g_cellsG + (size_t)cb*131072;
        x2a = g_x2G + ca*512; x2b = g_x2G + cb*512;
        Cout = g_CG + (size_t)mm*262144;
    }
    int r = lane & 15, quad = lane >> 4;
    const unsigned short* Ap = A + (size_t)(ti*16 + r)*256 + quad*8;
    const unsigned short* Bp = B + (size_t)(tj*16 + r)*256 + quad*8;
    floatx4 acc = {0.f, 0.f, 0.f, 0.f};
    #pragma unroll
    for (int k = 0; k < 256; k += 32) {
        short8 av = *(const short8*)(Ap + k);
        short8 bv = *(const short8*)(Bp + k);
        acc = __builtin_amdgcn_mfma_f32_16x16x32_bf16(av, bv, acc, 0, 0, 0);
    }
    int jc = tj*16 + r;                           // D: col = lane&15, row = quad*4 + reg
    float y2 = x2b[jc];
    #pragma unroll
    for (int rr = 0; rr < 4; rr++) {
        int ir = ti*16 + quad*4 + rr;
        float v = x2a[ir] + y2 - 2.f*acc[rr];
        Cout[(size_t)ir*m + jc] = (_Float16)(0.5f*fmaxf(v, 0.f));
    }
}

// ---------------- init: barriers, accumulators, eps table -------------------
__global__ void k_init() {
    int t = threadIdx.x;                          // 128 threads
    if (t < 36) g_bar[t] = 0u;
    if (t < 4)  g_acc[t] = 0.f;
    if (t < 122) {                                // same double math as reference
        double e = 1024.0 * pow(0.81, (double)t);
        if (e < 1e-8) e = 1e-8;
        g_efT[t] = (float)e;
        g_ivT[t] = (float)(1.0/e);
    }
}

// ---------------- barrier halves (relaxed monotonic counter) ----------------
__device__ __forceinline__ void bar_arrive(int gid) {
    // caller has drained its exchange stores (vmcnt) and __syncthreads'ed
    if (threadIdx.x == 0)
        __hip_atomic_fetch_add(&g_bar[gid], 1u, __ATOMIC_RELAXED, __HIP_MEMORY_SCOPE_AGENT);
}
__device__ __forceinline__ void bar_wait(int gid, unsigned tgt) {
    if (threadIdx.x == 0) {
        int guard = 0;
        while (__hip_atomic_load(&g_bar[gid], __ATOMIC_RELAXED, __HIP_MEMORY_SCOPE_AGENT) < tgt) {
            __builtin_amdgcn_s_sleep(1);
            if (++guard > 20000000) break;        // failsafe: never hang
        }
    }
    __syncthreads();
}

// ---------------- persistent solver: C LDS-resident, 123 rounds -------------
// 216 blocks x 512 thr, 152 KB LDS, 1 block/CU -> all co-resident.
// Jacobi independence: f_{k+1}=R(g_k), g_{k+1}=C(f_k) -> per-round pipeline
//   A: col-sweep(f_k) -> store partials -> ARRIVE (early)
//   B: row-sweep(g_k) -> f_{k+1}        (hides partner skew + store drain)
//   C: poll -> read partials -> combine -> g_{k+1}
extern __shared__ char smem[];
__global__ void __launch_bounds__(512) k_solve() {
    _Float16* sC = (_Float16*)smem;               // 131072 B
    float* scr  = (float*)(smem + 131072);        // 16384 B (role 0 tree)
    float* sg   = (float*)(smem + 147456);        // [2][512]
    float* sf   = (float*)(smem + 151552);        // [2][512] (role2 uses [2][128])
    float* sred = (float*)(smem + 155648);        // 8 floats
    int b = blockIdx.x, tid = threadIdx.x, lane = tid & 63, w = tid >> 6;

    int role, gid = -1, q = 0;
    const _Float16* Csrc; float loga;
    if (b < 112)      { role = 2; gid = b >> 2; q = b & 3;
                        Csrc = g_CG + (size_t)gid*262144 + (size_t)q*65536;
                        loga = -6.238324625039508f; }
    else if (b < 144) { role = 3; int t = b - 112; int c = t >> 2; q = t & 3; gid = 28 + c;
                        Csrc = g_CG + (size_t)(28+c)*262144 + (size_t)q*65536;
                        loga = -6.238324625039508f; }
    else if (b < 200) { role = 0; int p = b - 144;
                        Csrc = g_CL + (size_t)p*65536;
                        loga = -5.545177444479562f; }
    else              { role = 1; int c = b - 200;
                        Csrc = g_CL + (size_t)(56+c)*65536;
                        loga = -5.545177444479562f; }

    // ---- stage C into LDS (once), zero potentials ----
    for (int i = tid; i < 8192; i += 512)
        ((floatx4*)sC)[i] = ((const floatx4*)Csrc)[i];
    for (int i = tid; i < 1024; i += 512) { sg[i] = 0.f; sf[i] = 0.f; }
    __syncthreads();

    int po = 0;
    for (int round = 0; round < 123; round++) {
        int fin = (round == 122);
        int ei = fin ? 121 : round;
        float ef  = g_efT[ei];
        float inv = g_ivT[ei];
        int hard = (ef < 1e-5f) ? 1 : 0;
        float i2  = inv * LOG2E;
        float lg2 = loga * LOG2E;
        float meps = -ef * LN2;
        int pn = po ^ 1;
        int rb = round & 1;                       // exchange double-buffer

        if (role == 2) {                          // ---- global pair slice ----
            const float* fpo = sf + po*128;
            // ---- phase A: column sweep (uses f_k only), lane owns col tid --
            {
                float m2 = -3.4e38f, ss = 0.f;
                const _Float16* cp = sC + tid;
                if (!hard) {
                    #pragma unroll 4
                    for (int r = 0; r < 128; r++) {
                        float a2 = lg2 + fpo[r]*i2;
                        float u  = a2 - (float)cp[(size_t)r*512]*i2;
                        float mn = fmaxf(m2, u);
                        ss = ss*exp2f(m2-mn) + exp2f(u-mn);
                        m2 = mn;
                    }
                } else {
                    #pragma unroll 8
                    for (int r = 0; r < 128; r++) {
                        float a2 = lg2 + fpo[r]*i2;
                        m2 = fmaxf(m2, a2 - (float)cp[(size_t)r*512]*i2);
                    }
                }
                xst64(&g_xch[gid][rb][q][tid],
                      (unsigned long long)__float_as_uint(m2) |
                      ((unsigned long long)__float_as_uint(ss) << 32));
            }
            asm volatile("s_waitcnt vmcnt(0)" ::: "memory");
            __syncthreads();
            bar_arrive(gid);
            // ---- phase B: row sweep (uses g_k) -> f_{k+1} ------------------
            {
                const float* gp = sg + po*512;
                float* fpn = sf + pn*128;
                float h2[8];
                #pragma unroll
                for (int k = 0; k < 8; k++) h2[k] = lg2 + gp[lane*8+k]*i2;
                #pragma unroll 4
                for (int s = 0; s < 16; s++) {
                    int r = w*16 + s;
                    half8 cv = *(const half8*)(sC + (size_t)r*512 + lane*8);
                    float tv[8]; float mx = -3.4e38f;
                    #pragma unroll
                    for (int k = 0; k < 8; k++) {
                        float t = h2[k] - (float)cv[k]*i2;
                        tv[k] = t; mx = fmaxf(mx, t);
                    }
                    #pragma unroll
                    for (int o = 32; o; o >>= 1) mx = fmaxf(mx, __shfl_xor(mx, o));
                    float ft;
                    if (!hard) {
                        float sum = 0.f;
                        #pragma unroll
                        for (int k = 0; k < 8; k++) sum += exp2f(tv[k]-mx);
                        #pragma unroll
                        for (int o = 32; o; o >>= 1) sum += __shfl_xor(sum, o);
                        ft = meps*(mx + __log2f(sum));
                    } else ft = meps*mx;
                    if (lane == 0) fpn[r] = fin ? ft : 0.5f*(fpo[r] + ft);
                }
            }
            // ---- phase C: poll, read partials, combine -> g_{k+1} ----------
            bar_wait(gid, 4u*(unsigned)(round+1));
            {
                int c = tid;
                unsigned long long v0 = xld64(&g_xch[gid][rb][0][c]);
                unsigned long long v1 = xld64(&g_xch[gid][rb][1][c]);
                unsigned long long v2 = xld64(&g_xch[gid][rb][2][c]);
                unsigned long long v3 = xld64(&g_xch[gid][rb][3][c]);
                float a0 = __uint_as_float((unsigned)v0), b0 = __uint_as_float((unsigned)(v0 >> 32));
                float a1 = __uint_as_float((unsigned)v1), b1 = __uint_as_float((unsigned)(v1 >> 32));
                float a2m = __uint_as_float((unsigned)v2), b2 = __uint_as_float((unsigned)(v2 >> 32));
                float a3 = __uint_as_float((unsigned)v3), b3 = __uint_as_float((unsigned)(v3 >> 32));
                float m = fmaxf(fmaxf(a0, a1), fmaxf(a2m, a3));
                float gt;
                if (!hard) {
                    float s = b0*exp2f(a0-m) + b1*exp2f(a1-m) + b2*exp2f(a2m-m) + b3*exp2f(a3-m);
                    gt = meps*(m + __log2f(s));
                } else gt = meps*m;
                sg[pn*512+c] = fin ? gt : 0.5f*(sg[po*512+c] + gt);
            }
            __syncthreads();
        } else if (role == 3) {                   // ---- global Cxx slice ----
            const float* pp = sg + po*512;
            float h2[8];
            #pragma unroll
            for (int k = 0; k < 8; k++) h2[k] = lg2 + pp[lane*8+k]*i2;
            int gx = gid - 28;
            #pragma unroll 4
            for (int s = 0; s < 16; s++) {
                int r = w*16 + s;
                half8 cv = *(const half8*)(sC + (size_t)r*512 + lane*8);
                float tv[8]; float mx = -3.4e38f;
                #pragma unroll
                for (int k = 0; k < 8; k++) {
                    float t = h2[k] - (float)cv[k]*i2;
                    tv[k] = t; mx = fmaxf(mx, t);
                }
                #pragma unroll
                for (int o = 32; o; o >>= 1) mx = fmaxf(mx, __shfl_xor(mx, o));
                float ft;
                if (!hard) {
                    float sum = 0.f;
                    #pragma unroll
                    for (int k = 0; k < 8; k++) sum += exp2f(tv[k]-mx);
                    #pragma unroll
                    for (int o = 32; o; o >>= 1) sum += __shfl_xor(sum, o);
                    ft = meps*(mx + __log2f(sum));
                } else ft = meps*mx;
                if (lane == 0) {
                    float old = pp[q*128 + r];
                    xstf(&g_xpx[gx][rb][q][r], fin ? ft : 0.5f*(old + ft));
                }
            }
            asm volatile("s_waitcnt vmcnt(0)" ::: "memory");
            __syncthreads();
            bar_arrive(gid);
            bar_wait(gid, 4u*(unsigned)(round+1));
            { int c = tid; sg[pn*512+c] = xldf(&g_xpx[gx][rb][c>>7][c&127]); }
            __syncthreads();
        } else if (role == 0) {                   // ---- local pair (private) ----
            const float* gp = sg + po*512;
            const float* fpo = sf + po*512;
            float* fpn = sf + pn*512;
            int co = lane & 31, radd = lane >> 5;
            float h2[8];
            #pragma unroll
            for (int k = 0; k < 8; k++) h2[k] = lg2 + gp[co*8+k]*i2;
            float m2[8], ssv[8];
            #pragma unroll
            for (int k = 0; k < 8; k++) { m2[k] = -3.4e38f; ssv[k] = 0.f; }
            #pragma unroll 4
            for (int s = 0; s < 16; s++) {
                int row = w*32 + 2*s + radd;
                half8 cv = *(const half8*)(sC + row*256 + co*8);
                float fr = fpo[row];
                float a2 = lg2 + fr*i2;
                float tv[8]; float mx = -3.4e38f;
                #pragma unroll
                for (int k = 0; k < 8; k++) {
                    float d = (float)cv[k]*(-i2);
                    float t = h2[k] + d; tv[k] = t; mx = fmaxf(mx, t);
                    float u = a2 + d;
                    float mn = fmaxf(m2[k], u);
                    if (!hard) ssv[k] = ssv[k]*exp2f(m2[k]-mn) + exp2f(u-mn);
                    m2[k] = mn;
                }
                #pragma unroll
                for (int o = 16; o; o >>= 1) mx = fmaxf(mx, __shfl_xor(mx, o));
                float ft;
                if (!hard) {
                    float sum = 0.f;
                    #pragma unroll
                    for (int k = 0; k < 8; k++) sum += exp2f(tv[k]-mx);
                    #pragma unroll
                    for (int o = 16; o; o >>= 1) sum += __shfl_xor(sum, o);
                    ft = meps*(mx + __log2f(sum));
                } else ft = meps*mx;
                if ((lane & 31) == 0) fpn[row] = fin ? ft : 0.5f*(fr + ft);
            }
            #pragma unroll
            for (int k = 0; k < 8; k++) {         // merge half-waves (same cols)
                float mo = __shfl_xor(m2[k], 32), so = __shfl_xor(ssv[k], 32);
                float mn = fmaxf(m2[k], mo);
                if (!hard) ssv[k] = ssv[k]*exp2f(m2[k]-mn) + so*exp2f(mo-mn);
                m2[k] = mn;
            }
            if (w >= 4 && lane < 32) {
                float* pm = scr + (w-4)*256; float* ps = scr + 1024 + (w-4)*256;
                #pragma unroll
                for (int k = 0; k < 8; k++) { pm[co*8+k] = m2[k]; ps[co*8+k] = ssv[k]; }
            }
            __syncthreads();
            if (w < 4 && lane < 32) {
                const float* pm = scr + w*256; const float* ps = scr + 1024 + w*256;
                #pragma unroll
                for (int k = 0; k < 8; k++) {
                    float mo = pm[co*8+k], so = ps[co*8+k];
                    float mn = fmaxf(m2[k], mo);
                    if (!hard) ssv[k] = ssv[k]*exp2f(m2[k]-mn) + so*exp2f(mo-mn);
                    m2[k] = mn;
                }
            }
            __syncthreads();
            if (w >= 1 && w < 4 && lane < 32) {
                float* pm = scr + (w-1)*256; float* ps = scr + 1024 + (w-1)*256;
                #pragma unroll
                for (int k = 0; k < 8; k++) { pm[co*8+k] = m2[k]; ps[co*8+k] = ssv[k]; }
            }
            __syncthreads();
            if (w == 0 && lane < 32) {
                #pragma unroll
                for (int j = 0; j < 3; j++) {
                    const float* pm = scr + j*256; const float* ps = scr + 1024 + j*256;
                    #pragma unroll
                    for (int k = 0; k < 8; k++) {
                        float mo = pm[co*8+k], so = ps[co*8+k];
                        float mn = fmaxf(m2[k], mo);
                        if (!hard) ssv[k] = ssv[k]*exp2f(m2[k]-mn) + so*exp2f(mo-mn);
                        m2[k] = mn;
                    }
                }
                #pragma unroll
                for (int k = 0; k < 8; k++) {
                    int c = co*8 + k;
                    float gt = hard ? meps*m2[k] : meps*(m2[k] + __log2f(ssv[k]));
                    sg[pn*512+c] = fin ? gt : 0.5f*(sg[po*512+c] + gt);
                }
            }
            __syncthreads();
        } else {                                  // ---- local Cxx (private) ----
            const float* pp = sg + po*512;
            float* ppn = sg + pn*512;
            int co = lane & 31, radd = lane >> 5;
            float h2[8];
            #pragma unroll
            for (int k = 0; k < 8; k++) h2[k] = lg2 + pp[co*8+k]*i2;
            #pragma unroll 4
            for (int s = 0; s < 16; s++) {
                int row = w*32 + 2*s + radd;
                half8 cv = *(const half8*)(sC + row*256 + co*8);
                float tv[8]; float mx = -3.4e38f;
                #pragma unroll
                for (int k = 0; k < 8; k++) {
                    float t = h2[k] - (float)cv[k]*i2;
                    tv[k] = t; mx = fmaxf(mx, t);
                }
                #pragma unroll
                for (int o = 16; o; o >>= 1) mx = fmaxf(mx, __shfl_xor(mx, o));
                float ft;
                if (!hard) {
                    float sum = 0.f;
                    #pragma unroll
                    for (int k = 0; k < 8; k++) sum += exp2f(tv[k]-mx);
                    #pragma unroll
                    for (int o = 16; o; o >>= 1) sum += __shfl_xor(sum, o);
                    ft = meps*(mx + __log2f(sum));
                } else ft = meps*mx;
                if ((lane & 31) == 0) {
                    float old = pp[row];
                    ppn[row] = fin ? ft : 0.5f*(old + ft);
                }
            }
            __syncthreads();
        }
        po = pn;
    }

    // ---- final reduction: accumulate loss components ----
    float v = 0.f, v2 = 0.f; int idx, idx2 = -1;
    if (role == 0)      { if (tid < 256) v = sf[po*512+tid] + sg[po*512+tid]; idx = 0; }
    else if (role == 1) { if (tid < 256) v = sg[po*512+tid]; idx = 1; }
    else if (role == 2) { if (tid < 128) v = sf[po*128+tid]; idx = 2;
                          if (q == 0) { v2 = sg[po*512+tid]; idx2 = 2; } }
    else                { if (tid < 128) v = sg[po*512 + q*128 + tid]; idx = 3; }
    #pragma unroll
    for (int o = 32; o; o >>= 1) v += __shfl_xor(v, o);
    if ((tid & 63) == 0) sred[w] = v;
    __syncthreads();
    if (tid == 0) {
        float t = 0.f;
        #pragma unroll
        for (int i = 0; i < 8; i++) t += sred[i];
        atomicAdd(&g_acc[idx], t);
    }
    if (idx2 >= 0) {
        __syncthreads();
        #pragma unroll
        for (int o = 32; o; o >>= 1) v2 += __shfl_xor(v2, o);
        if ((tid & 63) == 0) sred[w] = v2;
        __syncthreads();
        if (tid == 0) {
            float t = 0.f;
            #pragma unroll
            for (int i = 0; i < 8; i++) t += sred[i];
            atomicAdd(&g_acc[idx2], t);
        }
    }
}

// ---------------- final combine ---------------------------------------------
__global__ void k_combine(float* __restrict__ out) {
    if (threadIdx.x == 0) {
        float SL = g_acc[0], PL = g_acc[1], SG = g_acc[2], PG = g_acc[3];
        out[0] = (SL/14336.f - PL/2048.f) + 0.5f*(SG/14336.f - PG/2048.f);
    }
}

// ---------------- host launcher ---------------------------------------------
extern "C" void kernel_launch(void* const* d_in, const int* in_sizes, int n_in,
                              void* d_out, int out_size, void* d_ws, size_t ws_size,
                              hipStream_t stream) {
    (void)in_sizes; (void)n_in; (void)out_size; (void)d_ws; (void)ws_size;
    const float* feat  = (const float*)d_in[0];
    const int* labels  = (const int*)d_in[1];
    const int* subg    = (const int*)d_in[2];

    static int attr_set = 0;
    if (!attr_set) {
        hipFuncSetAttribute((const void*)k_solve,
                            hipFuncAttributeMaxDynamicSharedMemorySize, 155712);
        attr_set = 1;
    }

    k_index <<<24,    64, 0, stream>>>(labels, subg);
    k_gather<<<2048, 256, 0, stream>>>(feat);
    k_gemm  <<<13824,256, 0, stream>>>();
    k_init  <<<1,    128, 0, stream>>>();
    k_solve <<<216,  512, 155712, stream>>>();
    k_combine<<<1,    64, 0, stream>>>((float*)d_out);
}